// Round 1
// baseline (4337.004 us; speedup 1.0000x reference)
//
#include <hip/hip_runtime.h>

#define BB 256
#define TT 2048
#define HD 100
#define G4 400   // 4*H

__device__ __forceinline__ float sigmoid_f(float x) {
    return 1.0f / (1.0f + __expf(-x));
}
__device__ __forceinline__ float tanh_f(float x) {
    // tanh(x) = 1 - 2/(e^{2x}+1); saturates cleanly to +-1, no NaN
    return 1.0f - 2.0f / (__expf(2.0f * x) + 1.0f);
}

// ---------------- Layer 1 ----------------
// grid = 256 blocks (one batch row each), 512 threads.
// Threads 0..399 own one gate column (weights in registers).
// Threads 0..99 additionally own the c_j state + h update.
__global__ __launch_bounds__(512, 2) void lstm_layer1(
    const float* __restrict__ x,      // [B][T][8]
    const float* __restrict__ w_ih,   // [400][8]
    const float* __restrict__ w_hh,   // [400][100]
    const float* __restrict__ b_ih,   // [400]
    const float* __restrict__ b_hh,   // [400]
    float* __restrict__ h_out,        // [Tc][B][100]
    float* __restrict__ h_state,      // [B][100]
    float* __restrict__ c_state,      // [B][100]
    int t0, int Tc, int first)
{
    const int b   = blockIdx.x;
    const int tid = threadIdx.x;

    __shared__ __align__(16) float h_lds[HD];
    __shared__ float gates[G4];
    __shared__ __align__(16) float x_lds[32 * 8];

    float wih[8];
    float whh[HD];
    float bias = 0.0f, c = 0.0f;

    if (tid < G4) {
        const float4* ip = (const float4*)(w_ih + (size_t)tid * 8);
        float4 i0 = ip[0], i1 = ip[1];
        wih[0]=i0.x; wih[1]=i0.y; wih[2]=i0.z; wih[3]=i0.w;
        wih[4]=i1.x; wih[5]=i1.y; wih[6]=i1.z; wih[7]=i1.w;
        const float4* hp = (const float4*)(w_hh + (size_t)tid * HD);
        #pragma unroll
        for (int kk = 0; kk < HD/4; ++kk) {
            float4 v = hp[kk];
            whh[4*kk+0]=v.x; whh[4*kk+1]=v.y; whh[4*kk+2]=v.z; whh[4*kk+3]=v.w;
        }
        bias = b_ih[tid] + b_hh[tid];
    }
    if (tid < HD) {
        h_lds[tid] = first ? 0.0f : h_state[(size_t)b*HD + tid];
        c          = first ? 0.0f : c_state[(size_t)b*HD + tid];
    }
    __syncthreads();

    for (int tt = 0; tt < Tc; ++tt) {
        const int t = t0 + tt;
        if ((tt & 31) == 0) {
            // stage x[b][t..t+32][0..8] (256 floats) into LDS
            if (tid < 64) {
                const float4* src = (const float4*)(x + ((size_t)b * TT + t) * 8);
                ((float4*)x_lds)[tid] = src[tid];
            }
            __syncthreads();
        }
        if (tid < G4) {
            float acc = bias;
            const float4 xa = *(const float4*)(x_lds + (tt & 31) * 8);
            const float4 xb = *(const float4*)(x_lds + (tt & 31) * 8 + 4);
            acc += xa.x*wih[0]; acc += xa.y*wih[1]; acc += xa.z*wih[2]; acc += xa.w*wih[3];
            acc += xb.x*wih[4]; acc += xb.y*wih[5]; acc += xb.z*wih[6]; acc += xb.w*wih[7];
            #pragma unroll
            for (int kk = 0; kk < HD/4; ++kk) {
                float4 hv = *(const float4*)(h_lds + 4*kk);
                acc += hv.x*whh[4*kk+0];
                acc += hv.y*whh[4*kk+1];
                acc += hv.z*whh[4*kk+2];
                acc += hv.w*whh[4*kk+3];
            }
            float a;
            if (tid < 200 || tid >= 300) a = sigmoid_f(acc);  // i, f, o gates
            else                          a = tanh_f(acc);    // g gate
            gates[tid] = a;
        }
        __syncthreads();
        if (tid < HD) {
            float gi = gates[tid];
            float gf = gates[HD   + tid];
            float gg = gates[2*HD + tid];
            float go = gates[3*HD + tid];
            c = gf * c + gi * gg;
            float h = go * tanh_f(c);
            h_lds[tid] = h;
            h_out[((size_t)tt * BB + b) * HD + tid] = h;
        }
        __syncthreads();
    }

    if (tid < HD) {
        h_state[(size_t)b*HD + tid] = h_lds[tid];
        c_state[(size_t)b*HD + tid] = c;
    }
}

// ---------------- Layer 2 ----------------
__global__ __launch_bounds__(512, 2) void lstm_layer2(
    const float* __restrict__ h1_buf, // [Tc][B][100]
    const float* __restrict__ w_ih,   // [400][100]
    const float* __restrict__ w_hh,   // [400][100]
    const float* __restrict__ b_ih,
    const float* __restrict__ b_hh,
    float* __restrict__ h_state,      // [B][100]
    float* __restrict__ c_state,      // [B][100]
    int Tc, int first)
{
    const int b   = blockIdx.x;
    const int tid = threadIdx.x;

    __shared__ __align__(16) float h2_lds[HD];
    __shared__ __align__(16) float h1_lds[2][104];
    __shared__ float gates[G4];

    float wih[HD];
    float whh[HD];
    float bias = 0.0f, c = 0.0f;

    if (tid < G4) {
        const float4* ip = (const float4*)(w_ih + (size_t)tid * HD);
        const float4* hp = (const float4*)(w_hh + (size_t)tid * HD);
        #pragma unroll
        for (int kk = 0; kk < HD/4; ++kk) {
            float4 v = ip[kk];
            wih[4*kk+0]=v.x; wih[4*kk+1]=v.y; wih[4*kk+2]=v.z; wih[4*kk+3]=v.w;
        }
        #pragma unroll
        for (int kk = 0; kk < HD/4; ++kk) {
            float4 v = hp[kk];
            whh[4*kk+0]=v.x; whh[4*kk+1]=v.y; whh[4*kk+2]=v.z; whh[4*kk+3]=v.w;
        }
        bias = b_ih[tid] + b_hh[tid];
    }
    if (tid < HD) {
        h2_lds[tid] = first ? 0.0f : h_state[(size_t)b*HD + tid];
        c           = first ? 0.0f : c_state[(size_t)b*HD + tid];
        h1_lds[0][tid] = h1_buf[(size_t)b * HD + tid];   // step 0 row
    }
    __syncthreads();

    int cur = 0;
    for (int tt = 0; tt < Tc; ++tt) {
        // prefetch next h1 row with otherwise-idle threads 400..499
        const int jj = tid - G4;
        float pre = 0.0f;
        if (jj >= 0 && jj < HD) {
            const int nt = (tt + 1 < Tc) ? (tt + 1) : tt;
            pre = h1_buf[((size_t)nt * BB + b) * HD + jj];
        }
        if (tid < G4) {
            float acc = bias;
            #pragma unroll
            for (int kk = 0; kk < HD/4; ++kk) {
                float4 hv = *(const float4*)(&h1_lds[cur][4*kk]);
                acc += hv.x*wih[4*kk+0];
                acc += hv.y*wih[4*kk+1];
                acc += hv.z*wih[4*kk+2];
                acc += hv.w*wih[4*kk+3];
            }
            #pragma unroll
            for (int kk = 0; kk < HD/4; ++kk) {
                float4 hv = *(const float4*)(h2_lds + 4*kk);
                acc += hv.x*whh[4*kk+0];
                acc += hv.y*whh[4*kk+1];
                acc += hv.z*whh[4*kk+2];
                acc += hv.w*whh[4*kk+3];
            }
            float a;
            if (tid < 200 || tid >= 300) a = sigmoid_f(acc);
            else                          a = tanh_f(acc);
            gates[tid] = a;
        }
        if (jj >= 0 && jj < HD) h1_lds[cur ^ 1][jj] = pre;
        __syncthreads();
        if (tid < HD) {
            float gi = gates[tid];
            float gf = gates[HD   + tid];
            float gg = gates[2*HD + tid];
            float go = gates[3*HD + tid];
            c = gf * c + gi * gg;
            float h = go * tanh_f(c);
            h2_lds[tid] = h;
        }
        __syncthreads();
        cur ^= 1;
    }

    if (tid < HD) {
        h_state[(size_t)b*HD + tid] = h2_lds[tid];
        c_state[(size_t)b*HD + tid] = c;
    }
}

// ---------------- FC head ----------------
__global__ void fc_head(const float* __restrict__ h2,     // [B][100]
                        const float* __restrict__ fc1_w,  // [25][100]
                        const float* __restrict__ fc1_b,  // [25]
                        const float* __restrict__ fc2_w,  // [1][25]
                        const float* __restrict__ fc2_b,  // [1]
                        float* __restrict__ out)          // [B]
{
    const int bidx = threadIdx.x;  // 0..255, one batch row each
    const float* h = h2 + (size_t)bidx * HD;
    float hv[HD];
    #pragma unroll
    for (int kk = 0; kk < HD/4; ++kk) {
        float4 v = *(const float4*)(h + 4*kk);
        hv[4*kk+0]=v.x; hv[4*kk+1]=v.y; hv[4*kk+2]=v.z; hv[4*kk+3]=v.w;
    }
    float y = fc2_b[0];
    #pragma unroll
    for (int m = 0; m < 25; ++m) {
        float a = fc1_b[m];
        const float* wp = fc1_w + m * HD;
        #pragma unroll
        for (int k = 0; k < HD; ++k) a += hv[k] * wp[k];
        y += a * fc2_w[m];
    }
    out[bidx] = y;
}

extern "C" void kernel_launch(void* const* d_in, const int* in_sizes, int n_in,
                              void* d_out, int out_size, void* d_ws, size_t ws_size,
                              hipStream_t stream) {
    const float* x     = (const float*)d_in[0];
    const float* w_ih1 = (const float*)d_in[1];
    const float* w_hh1 = (const float*)d_in[2];
    const float* b_ih1 = (const float*)d_in[3];
    const float* b_hh1 = (const float*)d_in[4];
    const float* w_ih2 = (const float*)d_in[5];
    const float* w_hh2 = (const float*)d_in[6];
    const float* b_ih2 = (const float*)d_in[7];
    const float* b_hh2 = (const float*)d_in[8];
    const float* fc1_w = (const float*)d_in[9];
    const float* fc1_b = (const float*)d_in[10];
    const float* fc2_w = (const float*)d_in[11];
    const float* fc2_b = (const float*)d_in[12];
    float* out = (float*)d_out;

    const size_t state_f = 4 * (size_t)BB * HD;   // h1s,c1s,h2s,c2s
    int Tc = 256;                                  // must divide T, multiple of 32
    while (Tc > 32 && ((size_t)Tc * BB * HD + state_f) * 4 > ws_size) Tc >>= 1;

    float* h1buf = (float*)d_ws;
    float* h1s = h1buf + (size_t)Tc * BB * HD;
    float* c1s = h1s + (size_t)BB * HD;
    float* h2s = c1s + (size_t)BB * HD;
    float* c2s = h2s + (size_t)BB * HD;

    const int nch = TT / Tc;
    for (int ch = 0; ch < nch; ++ch) {
        lstm_layer1<<<BB, 512, 0, stream>>>(x, w_ih1, w_hh1, b_ih1, b_hh1,
                                            h1buf, h1s, c1s, ch * Tc, Tc, ch == 0);
        lstm_layer2<<<BB, 512, 0, stream>>>(h1buf, w_ih2, w_hh2, b_ih2, b_hh2,
                                            h2s, c2s, Tc, ch == 0);
    }
    fc_head<<<1, 256, 0, stream>>>(h2s, fc1_w, fc1_b, fc2_w, fc2_b, out);
}

// Round 2
// 2923.470 us; speedup vs baseline: 1.4835x; 1.4835x over previous
//
#include <hip/hip_runtime.h>

#define BB 256
#define TT 2048
#define HD 100
#define NG 400

typedef _Float16 h2v __attribute__((ext_vector_type(2)));

__device__ __forceinline__ float fdot2u(unsigned a, unsigned b, float c) {
#if __has_builtin(__builtin_amdgcn_fdot2)
    return __builtin_amdgcn_fdot2(__builtin_bit_cast(h2v, a),
                                  __builtin_bit_cast(h2v, b), c, false);
#else
    h2v av = __builtin_bit_cast(h2v, a), bv = __builtin_bit_cast(h2v, b);
    c = fmaf((float)av[0], (float)bv[0], c);
    c = fmaf((float)av[1], (float)bv[1], c);
    return c;
#endif
}
__device__ __forceinline__ unsigned packh2(float a, float b) {
    h2v p; p[0] = (_Float16)a; p[1] = (_Float16)b;
    return __builtin_bit_cast(unsigned, p);
}
__device__ __forceinline__ float sigmoid_f(float x) {
    return 1.0f / (1.0f + __expf(-x));
}
__device__ __forceinline__ float tanh_f(float x) {
    return 1.0f - 2.0f / (__expf(2.0f * x) + 1.0f);
}

// One block per batch row. 896 threads = 14 waves.
//   tid   0..399 : layer-1 gate threads (one gate row each)
//   tid 400..431 : x prefetch loaders (idle lanes of wave 6)
//   tid 448..847 : layer-2 gate threads (one gate row each)
//   tid   0..99  : layer-1 c/h update;  tid 448..547 : layer-2 c/h update
// Software pipeline: iteration i computes L1 step i and L2 step i-1.
__global__ __launch_bounds__(896, 4) void lstm_fused(
    const float* __restrict__ x,
    const float* __restrict__ w_ih1, const float* __restrict__ w_hh1,
    const float* __restrict__ b_ih1, const float* __restrict__ b_hh1,
    const float* __restrict__ w_ih2, const float* __restrict__ w_hh2,
    const float* __restrict__ b_ih2, const float* __restrict__ b_hh2,
    const float* __restrict__ fc1_w, const float* __restrict__ fc1_b,
    const float* __restrict__ fc2_w, const float* __restrict__ fc2_b,
    float* __restrict__ out)
{
    const int b   = blockIdx.x;
    const int tid = threadIdx.x;

    __shared__ __align__(16) unsigned h1p[52];        // h1 packed f16x2 (+zero pad)
    __shared__ __align__(16) unsigned h2p[52];        // h2 packed f16x2
    __shared__ __align__(16) unsigned xb[2][32][4];   // x packed f16x2, dbuf
    __shared__ float g1[NG];
    __shared__ float g2[NG];
    __shared__ float h2f[HD];
    __shared__ float fca[25];

    const bool isG1 = (tid < NG);
    const int  g2i  = tid - 448;
    const bool isG2 = (g2i >= 0 && g2i < NG);
    const bool isLd = (tid >= 400 && tid < 432);
    const bool isU1 = (tid < HD);
    const bool isU2 = (g2i >= 0 && g2i < HD);

    unsigned wa[52], wb[52];  // packed weights: L1: wa=w_hh1 row; L2: wa=w_ih2, wb=w_hh2
    unsigned wx[4];           // L1: packed w_ih1 row (8 inputs)
    float bias = 0.0f, c = 0.0f;

    if (isG1) {
        const float4* ip = (const float4*)(w_ih1 + (size_t)tid * 8);
        float4 v0 = ip[0], v1 = ip[1];
        wx[0] = packh2(v0.x, v0.y); wx[1] = packh2(v0.z, v0.w);
        wx[2] = packh2(v1.x, v1.y); wx[3] = packh2(v1.z, v1.w);
        const float4* hp = (const float4*)(w_hh1 + (size_t)tid * HD);
        #pragma unroll
        for (int k2 = 0; k2 < 25; ++k2) {
            float4 v = hp[k2];
            wa[2*k2]   = packh2(v.x, v.y);
            wa[2*k2+1] = packh2(v.z, v.w);
        }
        wa[50] = 0u; wa[51] = 0u;
        bias = b_ih1[tid] + b_hh1[tid];
    }
    if (isG2) {
        const float4* ip = (const float4*)(w_ih2 + (size_t)g2i * HD);
        const float4* hp = (const float4*)(w_hh2 + (size_t)g2i * HD);
        #pragma unroll
        for (int k2 = 0; k2 < 25; ++k2) {
            float4 v = ip[k2];
            wa[2*k2]   = packh2(v.x, v.y);
            wa[2*k2+1] = packh2(v.z, v.w);
        }
        #pragma unroll
        for (int k2 = 0; k2 < 25; ++k2) {
            float4 v = hp[k2];
            wb[2*k2]   = packh2(v.x, v.y);
            wb[2*k2+1] = packh2(v.z, v.w);
        }
        wa[50] = wa[51] = wb[50] = wb[51] = 0u;
        bias = b_ih2[g2i] + b_hh2[g2i];
    }

    if (tid < 52) h1p[tid] = 0u;
    else if (tid >= 64 && tid < 116) h2p[tid - 64] = 0u;
    if (isLd) {   // stage x steps 0..31 into buf 0
        const int s = tid - 400;
        const float4* xp = (const float4*)(x + ((size_t)b * TT + s) * 8);
        float4 a0 = xp[0], a1 = xp[1];
        xb[0][s][0] = packh2(a0.x, a0.y); xb[0][s][1] = packh2(a0.z, a0.w);
        xb[0][s][2] = packh2(a1.x, a1.y); xb[0][s][3] = packh2(a1.z, a1.w);
    }
    __syncthreads();

    float4 pa = {0,0,0,0}, pb = {0,0,0,0};

    #pragma unroll 1
    for (int i = 0; i <= TT; ++i) {
        const bool pf = ((i & 31) == 0) && (i + 32 < TT);
        // ---------------- phase 1: gates ----------------
        if (isG1 && i < TT) {
            const unsigned* xq = xb[(i >> 5) & 1][i & 31];
            float a0 = bias, a1 = 0.0f;
            a0 = fdot2u(wx[0], xq[0], a0);
            a1 = fdot2u(wx[1], xq[1], a1);
            a0 = fdot2u(wx[2], xq[2], a0);
            a1 = fdot2u(wx[3], xq[3], a1);
            #pragma unroll
            for (int cI = 0; cI < 13; ++cI) {
                uint4 hv = ((const uint4*)h1p)[cI];
                a0 = fdot2u(wa[4*cI+0], hv.x, a0);
                a1 = fdot2u(wa[4*cI+1], hv.y, a1);
                a0 = fdot2u(wa[4*cI+2], hv.z, a0);
                a1 = fdot2u(wa[4*cI+3], hv.w, a1);
            }
            float acc = a0 + a1;
            g1[tid] = (tid < 200 || tid >= 300) ? sigmoid_f(acc) : tanh_f(acc);
        }
        if (isLd && pf) {   // issue next-chunk x loads (latency hides under gates)
            const float4* xp = (const float4*)(x + ((size_t)b * TT + (i + 32) + (tid - 400)) * 8);
            pa = xp[0]; pb = xp[1];
        }
        if (isG2 && i >= 1) {
            float a0 = bias, a1 = 0.0f;
            #pragma unroll
            for (int cI = 0; cI < 13; ++cI) {
                uint4 hv = ((const uint4*)h1p)[cI];
                a0 = fdot2u(wa[4*cI+0], hv.x, a0);
                a1 = fdot2u(wa[4*cI+1], hv.y, a1);
                a0 = fdot2u(wa[4*cI+2], hv.z, a0);
                a1 = fdot2u(wa[4*cI+3], hv.w, a1);
            }
            #pragma unroll
            for (int cI = 0; cI < 13; ++cI) {
                uint4 hv = ((const uint4*)h2p)[cI];
                a0 = fdot2u(wb[4*cI+0], hv.x, a0);
                a1 = fdot2u(wb[4*cI+1], hv.y, a1);
                a0 = fdot2u(wb[4*cI+2], hv.z, a0);
                a1 = fdot2u(wb[4*cI+3], hv.w, a1);
            }
            float acc = a0 + a1;
            g2[g2i] = (g2i < 200 || g2i >= 300) ? sigmoid_f(acc) : tanh_f(acc);
        }
        __syncthreads();
        // ---------------- phase 2: state update + x LDS write ----------------
        if (isU1 && i < TT) {
            float gi = g1[tid], gf = g1[HD + tid], gg = g1[2*HD + tid], go = g1[3*HD + tid];
            c = gf * c + gi * gg;
            float h = go * tanh_f(c);
            reinterpret_cast<_Float16*>(h1p)[tid] = (_Float16)h;
        }
        if (isU2 && i >= 1) {
            float gi = g2[g2i], gf = g2[HD + g2i], gg = g2[2*HD + g2i], go = g2[3*HD + g2i];
            c = gf * c + gi * gg;
            float h = go * tanh_f(c);
            reinterpret_cast<_Float16*>(h2p)[g2i] = (_Float16)h;
            if (i == TT) h2f[g2i] = h;
        }
        if (isLd && pf) {
            const int s  = tid - 400;
            const int nb = ((i >> 5) + 1) & 1;
            xb[nb][s][0] = packh2(pa.x, pa.y); xb[nb][s][1] = packh2(pa.z, pa.w);
            xb[nb][s][2] = packh2(pb.x, pb.y); xb[nb][s][3] = packh2(pb.z, pb.w);
        }
        __syncthreads();
    }

    // ---------------- FC head ----------------
    if (tid < 25) {
        float a = fc1_b[tid];
        const float* wp = fc1_w + tid * HD;
        #pragma unroll
        for (int k = 0; k < HD; ++k) a += h2f[k] * wp[k];
        fca[tid] = a;
    }
    __syncthreads();
    if (tid == 0) {
        float y = fc2_b[0];
        #pragma unroll
        for (int m = 0; m < 25; ++m) y += fca[m] * fc2_w[m];
        out[b] = y;
    }
}

extern "C" void kernel_launch(void* const* d_in, const int* in_sizes, int n_in,
                              void* d_out, int out_size, void* d_ws, size_t ws_size,
                              hipStream_t stream) {
    const float* x     = (const float*)d_in[0];
    const float* w_ih1 = (const float*)d_in[1];
    const float* w_hh1 = (const float*)d_in[2];
    const float* b_ih1 = (const float*)d_in[3];
    const float* b_hh1 = (const float*)d_in[4];
    const float* w_ih2 = (const float*)d_in[5];
    const float* w_hh2 = (const float*)d_in[6];
    const float* b_ih2 = (const float*)d_in[7];
    const float* b_hh2 = (const float*)d_in[8];
    const float* fc1_w = (const float*)d_in[9];
    const float* fc1_b = (const float*)d_in[10];
    const float* fc2_w = (const float*)d_in[11];
    const float* fc2_b = (const float*)d_in[12];
    float* out = (float*)d_out;

    lstm_fused<<<BB, 896, 0, stream>>>(x, w_ih1, w_hh1, b_ih1, b_hh1,
                                       w_ih2, w_hh2, b_ih2, b_hh2,
                                       fc1_w, fc1_b, fc2_w, fc2_b, out);
}